// Round 1
// baseline (11.336 us; speedup 1.0000x reference)
//
#include <hip/hip_runtime.h>

#define N_LAYERS 32
#define SEL_K 24
#define N_CHOICES 9   // N_LAYERS - SEL_K + 1
#define BATCH 32
#define DIM 4096
#define G_EPS 1e-10f

__global__ __launch_bounds__(256) void layer_selector_kernel(
    const float* __restrict__ feat,    // [B, L, D]
    const float* __restrict__ logits,  // [N_CHOICES]
    const float* __restrict__ noise,   // [B, N_CHOICES]
    float* __restrict__ out)           // [B*SEL_K*D] selected ++ [B*N_CHOICES] probs
{
    const int bk = blockIdx.x;
    const int b = bk / SEL_K;
    const int k = bk % SEL_K;

    __shared__ int s_idx;
    __shared__ float s_p;
    __shared__ float s_probs[N_CHOICES];

    if (threadIdx.x == 0) {
        float x[N_CHOICES];
        float m = -1e30f;
        #pragma unroll
        for (int c = 0; c < N_CHOICES; ++c) {
            float u = noise[b * N_CHOICES + c];
            float g = -logf(-logf(u + G_EPS) + G_EPS);
            x[c] = logits[c] + g;           // tau = 1.0
            m = fmaxf(m, x[c]);
        }
        float sum = 0.f;
        #pragma unroll
        for (int c = 0; c < N_CHOICES; ++c) {
            x[c] = expf(x[c] - m);          // jax.nn.softmax numerics: exp(x - max)
            sum += x[c];
        }
        int idx = 0;
        float best = -1.f;
        #pragma unroll
        for (int c = 0; c < N_CHOICES; ++c) {
            float y = x[c] / sum;           // y_soft
            if (y > best) { best = y; idx = c; }   // strict > == first-occurrence argmax
        }
        s_idx = idx;
        s_p = (1.0f + best) - best;         // y_hard + y_soft - y_soft at argmax
        #pragma unroll
        for (int c = 0; c < N_CHOICES; ++c)
            s_probs[c] = (c == idx) ? s_p : 0.0f;  // exactly 0 elsewhere: (0+s)-s == 0
    }
    __syncthreads();

    const int idx = s_idx;
    const float p = s_p;

    // Scaled row copy: selected[b,k,:] = p * feat[b, idx+k, :]
    const float4* __restrict__ src =
        (const float4*)(feat + ((size_t)b * N_LAYERS + (size_t)(idx + k)) * DIM);
    float4* __restrict__ dst =
        (float4*)(out + ((size_t)b * SEL_K + (size_t)k) * DIM);

    #pragma unroll
    for (int i = threadIdx.x; i < DIM / 4; i += 256) {
        float4 v = src[i];
        v.x *= p; v.y *= p; v.z *= p; v.w *= p;
        dst[i] = v;
    }

    // One block per b (k==0) writes the selection_probs output tail.
    if (k == 0 && threadIdx.x < N_CHOICES) {
        out[(size_t)BATCH * SEL_K * DIM + (size_t)b * N_CHOICES + threadIdx.x] =
            s_probs[threadIdx.x];
    }
}

extern "C" void kernel_launch(void* const* d_in, const int* in_sizes, int n_in,
                              void* d_out, int out_size, void* d_ws, size_t ws_size,
                              hipStream_t stream) {
    const float* feat   = (const float*)d_in[0];  // (32, 32, 4096) f32
    const float* logits = (const float*)d_in[1];  // (9,) f32
    const float* noise  = (const float*)d_in[2];  // (32, 9) f32
    float* out = (float*)d_out;

    dim3 grid(BATCH * SEL_K);
    dim3 block(256);
    hipLaunchKernelGGL(layer_selector_kernel, grid, block, 0, stream,
                       feat, logits, noise, out);
}